// Round 3
// baseline (511.455 us; speedup 1.0000x reference)
//
#include <hip/hip_runtime.h>
#include <hip/hip_bf16.h>

typedef __bf16 bf16_t;
typedef __bf16 bf16x8 __attribute__((ext_vector_type(8)));
typedef float  f32x4  __attribute__((ext_vector_type(4)));

static constexpr int M_ = 8192;   // 4 * 2048
static constexpr int N_ = 4096;   // out_f
static constexpr int K_ = 4096;   // in_f

// GEMM geometry: 256x256 tile, BK=64, 8 waves (2M x 4N), 512 threads.
static constexpr int BM = 256, BN = 256, BK = 64;
static constexpr int NT = K_ / BK;             // 64 K-tiles
static constexpr int HT_ELEMS  = 128 * 64;     // 8192 elems per half-tile
static constexpr int BUF_ELEMS = 2 * HT_ELEMS; // 16384 elems per K-tile buffer

// async global->LDS, 16B per lane. LDS dest must be wave-uniform base + lane*16.
__device__ __forceinline__ void load_lds16(const bf16_t* g, bf16_t* l) {
  __builtin_amdgcn_global_load_lds(
      (const __attribute__((address_space(1))) void*)g,
      (__attribute__((address_space(3))) void*)l,
      16, 0, 0);
}

#define MFMA16(a, b, c) __builtin_amdgcn_mfma_f32_16x16x32_bf16((a), (b), (c), 0, 0, 0)

// ---- pass 1: x fp32 -> bf16 ----------------------------------------------
__global__ __launch_bounds__(256) void cvt_x_kernel(const float* __restrict__ x,
                                                    bf16_t* __restrict__ xb) {
  const size_t i = ((size_t)blockIdx.x * 256 + threadIdx.x) * 8;
  const float4 f0 = *(const float4*)(x + i);
  const float4 f1 = *(const float4*)(x + i + 4);
  bf16x8 o;
  o[0] = (bf16_t)f0.x; o[1] = (bf16_t)f0.y; o[2] = (bf16_t)f0.z; o[3] = (bf16_t)f0.w;
  o[4] = (bf16_t)f1.x; o[5] = (bf16_t)f1.y; o[6] = (bf16_t)f1.z; o[7] = (bf16_t)f1.w;
  *(bf16x8*)(xb + i) = o;
}

// ---- pass 2: W[o][i] = q[o][i] * scales[o][i/128] -> bf16 ----------------
__global__ __launch_bounds__(256) void dequant_kernel(const int* __restrict__ q,
                                                      const float* __restrict__ s,
                                                      bf16_t* __restrict__ wb) {
  const size_t base = ((size_t)blockIdx.x * 256 + threadIdx.x) * 8;
  const int o  = (int)(base >> 12);
  const int ii = (int)(base & 4095);
  const float sc = s[(o << 5) + (ii >> 7)];
  const int4 q0 = *(const int4*)(q + base);
  const int4 q1 = *(const int4*)(q + base + 4);
  bf16x8 w;
  w[0] = (bf16_t)((float)q0.x * sc); w[1] = (bf16_t)((float)q0.y * sc);
  w[2] = (bf16_t)((float)q0.z * sc); w[3] = (bf16_t)((float)q0.w * sc);
  w[4] = (bf16_t)((float)q1.x * sc); w[5] = (bf16_t)((float)q1.y * sc);
  w[6] = (bf16_t)((float)q1.z * sc); w[7] = (bf16_t)((float)q1.w * sc);
  *(bf16x8*)(wb + base) = w;
}

// ---- pass 3: C = A . B^T + bias, balanced 8-phase (8/4/8/4 ds_reads) -----
// Fragment interleave:
//   A frag i (0..7): row = (i>>2)*128 + (i&3)*32 + wm*16
//   B frag j (0..3): row = (j>>1)*128 + wn*32 + (j&1)*16
// Phase 4 of tile T issues tile T+1's B-half0 reads (data provably resident
// after the vmcnt(6)+barrier) so every phase carries 4-8 ds_reads under MFMA.
// T-loop unrolled x2: compile-time buffer parity, no dynamic reg indexing.
__global__ __launch_bounds__(512, 2) void gemm_kernel(const bf16_t* __restrict__ A,
                                                      const bf16_t* __restrict__ B,
                                                      const float* __restrict__ bias,
                                                      float* __restrict__ C) {
  __shared__ __align__(16) bf16_t As[2 * BUF_ELEMS];  // 64 KiB
  __shared__ __align__(16) bf16_t Bs[2 * BUF_ELEMS];  // 64 KiB

  const int tid  = threadIdx.x;
  const int lane = tid & 63;
  const int wave = tid >> 6;
  const int ln = lane & 15;
  const int lq = lane >> 4;
  const int wm = wave >> 2;   // 0..1
  const int wn = wave & 3;    // 0..3

  // T1: XCD-bijective swizzle (512 wgs = 8 XCD x 64).
  const int bid = blockIdx.x;
  const int wg  = (bid & 7) * 64 + (bid >> 3);
  const int bn  = (wg & 15) * BN;
  const int bm  = (wg >> 4) * BM;

  // staging: thread t covers row (t>>3) of a 64-row chunk, 16B at inverse-swizzled col.
  const int r_sub = tid >> 3;
  const int g_col = ((tid & 7) ^ (r_sub & 7)) * 8;
  const size_t a_base = (size_t)(bm + r_sub) * K_ + g_col;
  const size_t b_base = (size_t)(bn + r_sub) * K_ + g_col;
  const int lds_off = tid * 8;

  auto stageA = [&](int t, int h) {
    bf16_t* d = As + (t & 1) * BUF_ELEMS + h * HT_ELEMS + lds_off;
    const bf16_t* s = A + a_base + (size_t)(h * 128) * K_ + (size_t)t * BK;
    load_lds16(s, d);
    load_lds16(s + (size_t)64 * K_, d + 4096);
  };
  auto stageB = [&](int t, int h) {
    bf16_t* d = Bs + (t & 1) * BUF_ELEMS + h * HT_ELEMS + lds_off;
    const bf16_t* s = B + b_base + (size_t)(h * 128) * K_ + (size_t)t * BK;
    load_lds16(s, d);
    load_lds16(s + (size_t)64 * K_, d + 4096);
  };

  // ds_read addressing (T2 swizzle on the k-column within each 64-elem row)
  const int kx0 = (lq * 8) ^ ((ln & 7) * 8);
  const int kx1 = (32 + lq * 8) ^ ((ln & 7) * 8);
  const int a_row_off = (wm * 16 + ln) * 64;
  const int b_row_off = (wn * 32 + ln) * 64;

  f32x4 acc[8][4] = {};
  bf16x8 bq0[2][2], bq1[2][2];   // B-half0 double set (cur/next across tiles)

// One K-tile: 4 phases x 16 MFMA. BQC_ = this tile's B-half0 (pre-read),
// BQN_ = next tile's B-half0 (read in phase 4 here).
#define TILE_BODY(T_, AS_, BS_, BQC_, BQN_)                                    \
  {                                                                            \
    const bf16_t* as = (AS_);                                                  \
    const bf16_t* bs = (BS_);                                                  \
    bf16x8 af[4][2], bqB[2][2];                                                \
    /* phase 1: read A-half0 (8); stage A1[T+1]; mfma i0-3 x j0-1 */           \
    _Pragma("unroll")                                                          \
    for (int i = 0; i < 4; ++i) {                                              \
      const bf16_t* p = as + a_row_off + i * 2048;                             \
      af[i][0] = *(const bf16x8*)(p + kx0);                                    \
      af[i][1] = *(const bf16x8*)(p + kx1);                                    \
    }                                                                          \
    if ((T_) + 1 < NT) stageA((T_) + 1, 1);                                    \
    asm volatile("s_waitcnt lgkmcnt(8)" ::: "memory");                         \
    __builtin_amdgcn_s_barrier();                                              \
    asm volatile("s_waitcnt lgkmcnt(0)" ::: "memory");                         \
    __builtin_amdgcn_sched_barrier(0);                                         \
    __builtin_amdgcn_s_setprio(1);                                             \
    _Pragma("unroll")                                                          \
    for (int i = 0; i < 4; ++i)                                                \
      _Pragma("unroll")                                                        \
      for (int j = 0; j < 2; ++j) {                                            \
        acc[i][j] = MFMA16(af[i][0], BQC_[j][0], acc[i][j]);                   \
        acc[i][j] = MFMA16(af[i][1], BQC_[j][1], acc[i][j]);                   \
      }                                                                        \
    __builtin_amdgcn_s_setprio(0);                                             \
    __builtin_amdgcn_s_barrier();                                              \
    /* phase 2: read B-half1 (4); stage A0[T+2]; mfma i0-3 x j2-3 */           \
    _Pragma("unroll")                                                          \
    for (int j = 0; j < 2; ++j) {                                              \
      const bf16_t* p = bs + HT_ELEMS + b_row_off + j * 1024;                  \
      bqB[j][0] = *(const bf16x8*)(p + kx0);                                   \
      bqB[j][1] = *(const bf16x8*)(p + kx1);                                   \
    }                                                                          \
    if ((T_) + 2 < NT) stageA((T_) + 2, 0);                                    \
    __builtin_amdgcn_s_barrier();                                              \
    asm volatile("s_waitcnt lgkmcnt(0)" ::: "memory");                         \
    __builtin_amdgcn_sched_barrier(0);                                         \
    __builtin_amdgcn_s_setprio(1);                                             \
    _Pragma("unroll")                                                          \
    for (int i = 0; i < 4; ++i)                                                \
      _Pragma("unroll")                                                        \
      for (int j = 0; j < 2; ++j) {                                            \
        acc[i][j + 2] = MFMA16(af[i][0], bqB[j][0], acc[i][j + 2]);            \
        acc[i][j + 2] = MFMA16(af[i][1], bqB[j][1], acc[i][j + 2]);            \
      }                                                                        \
    __builtin_amdgcn_s_setprio(0);                                             \
    __builtin_amdgcn_s_barrier();                                              \
    /* phase 3: read A-half1 (8, reuse af); stage B0[T+2]; mfma i4-7 x j2-3 */ \
    _Pragma("unroll")                                                          \
    for (int i = 0; i < 4; ++i) {                                              \
      const bf16_t* p = as + HT_ELEMS + a_row_off + i * 2048;                  \
      af[i][0] = *(const bf16x8*)(p + kx0);                                    \
      af[i][1] = *(const bf16x8*)(p + kx1);                                    \
    }                                                                          \
    if ((T_) + 2 < NT) stageB((T_) + 2, 0);                                    \
    __builtin_amdgcn_s_barrier();                                              \
    asm volatile("s_waitcnt lgkmcnt(0)" ::: "memory");                         \
    __builtin_amdgcn_sched_barrier(0);                                         \
    __builtin_amdgcn_s_setprio(1);                                             \
    _Pragma("unroll")                                                          \
    for (int i = 0; i < 4; ++i)                                                \
      _Pragma("unroll")                                                        \
      for (int j = 0; j < 2; ++j) {                                            \
        acc[i + 4][j + 2] = MFMA16(af[i][0], bqB[j][0], acc[i + 4][j + 2]);    \
        acc[i + 4][j + 2] = MFMA16(af[i][1], bqB[j][1], acc[i + 4][j + 2]);    \
      }                                                                        \
    __builtin_amdgcn_s_setprio(0);                                             \
    __builtin_amdgcn_s_barrier();                                              \
    /* phase 4: stage B1[T+2]; counted vmcnt; carried B0[T+1] reads (4);       \
       mfma i4-7 x j0-1 */                                                     \
    if ((T_) + 2 < NT) {                                                       \
      stageB((T_) + 2, 1);                                                     \
      asm volatile("s_waitcnt vmcnt(6)" ::: "memory");                         \
    } else {                                                                   \
      asm volatile("s_waitcnt vmcnt(0)" ::: "memory");                         \
    }                                                                          \
    __builtin_amdgcn_s_barrier();                                              \
    if ((T_) + 1 < NT) {                                                       \
      const bf16_t* nbs = ((T_) + 1) & 1 ? Bs + BUF_ELEMS : Bs;                \
      _Pragma("unroll")                                                        \
      for (int j = 0; j < 2; ++j) {                                            \
        const bf16_t* p = nbs + b_row_off + j * 1024;                          \
        BQN_[j][0] = *(const bf16x8*)(p + kx0);                                \
        BQN_[j][1] = *(const bf16x8*)(p + kx1);                                \
      }                                                                        \
    }                                                                          \
    __builtin_amdgcn_sched_barrier(0);                                         \
    __builtin_amdgcn_s_setprio(1);                                             \
    _Pragma("unroll")                                                          \
    for (int i = 0; i < 4; ++i)                                                \
      _Pragma("unroll")                                                        \
      for (int j = 0; j < 2; ++j) {                                            \
        acc[i + 4][j] = MFMA16(af[i][0], BQC_[j][0], acc[i + 4][j]);           \
        acc[i + 4][j] = MFMA16(af[i][1], BQC_[j][1], acc[i + 4][j]);           \
      }                                                                        \
    __builtin_amdgcn_s_setprio(0);                                             \
    __builtin_amdgcn_s_barrier();                                              \
  }

  // prologue: tile0 {A0,B0,B1,A1} + tile1 {A0,B0,B1}; retire tile0 (8 loads),
  // 3 half-tiles (6 loads) stay in flight; then pre-read B0[0].
  stageA(0, 0); stageB(0, 0); stageB(0, 1); stageA(0, 1);
  stageA(1, 0); stageB(1, 0); stageB(1, 1);
  asm volatile("s_waitcnt vmcnt(6)" ::: "memory");
  __builtin_amdgcn_s_barrier();
#pragma unroll
  for (int j = 0; j < 2; ++j) {
    const bf16_t* p = Bs + b_row_off + j * 1024;
    bq0[j][0] = *(const bf16x8*)(p + kx0);
    bq0[j][1] = *(const bf16x8*)(p + kx1);
  }

  for (int T = 0; T < NT; T += 2) {
    TILE_BODY(T,     As,             Bs,             bq0, bq1)
    TILE_BODY(T + 1, As + BUF_ELEMS, Bs + BUF_ELEMS, bq1, bq0)
  }
#undef TILE_BODY

  // ---- epilogue: LDS-coalesced C store (dwordx4), 4 chunks of 64 rows ----
  float bv[4];
#pragma unroll
  for (int j = 0; j < 4; ++j)
    bv[j] = bias[bn + (j >> 1) * 128 + wn * 32 + (j & 1) * 16 + ln];

  float* lds_f = (float*)As;            // 64 KiB = 64 rows x 256 cols fp32
  const int cb = wn * 32 + ln;
#pragma unroll
  for (int c = 0; c < 4; ++c) {
#pragma unroll
    for (int ih = 0; ih < 2; ++ih) {
      const int i = 2 * c + ih;
      const int rbase = ih * 32 + wm * 16 + lq * 4;
#pragma unroll
      for (int j = 0; j < 4; ++j) {
        const int cl = (j >> 1) * 128 + (j & 1) * 16 + cb;
#pragma unroll
        for (int r = 0; r < 4; ++r) {
          const int rl = rbase + r;
          const int pc = cl ^ (((rl >> 2) & 1) << 4);  // 2-way max on write
          lds_f[rl * 256 + pc] = acc[i][j][r] + bv[j];
        }
      }
    }
    asm volatile("s_waitcnt lgkmcnt(0)" ::: "memory");
    __builtin_amdgcn_s_barrier();
#pragma unroll
    for (int k = 0; k < 8; ++k) {
      const int rr = k * 8 + wave;
      const int pc = (lane * 4) ^ (((rr >> 2) & 1) << 4);
      const float4 v = *(const float4*)(lds_f + rr * 256 + pc);
      *(float4*)(C + (size_t)(bm + c * 64 + rr) * N_ + bn + lane * 4) = v;
    }
    if (c < 3) {
      asm volatile("s_waitcnt lgkmcnt(0)" ::: "memory");
      __builtin_amdgcn_s_barrier();
    }
  }
}

extern "C" void kernel_launch(void* const* d_in, const int* in_sizes, int n_in,
                              void* d_out, int out_size, void* d_ws, size_t ws_size,
                              hipStream_t stream) {
  const float* x    = (const float*)d_in[0];  // [4,2048,4096] fp32
  const int*   qw   = (const int*)d_in[1];    // [4096,4096] int32 in [0,16)
  const float* sc   = (const float*)d_in[2];  // [4096,32] fp32
  const float* bias = (const float*)d_in[3];  // [4096] fp32
  float* out = (float*)d_out;                 // [8192,4096] fp32

  bf16_t* xb = (bf16_t*)d_ws;                 // M_*K_ bf16 = 64 MiB
  bf16_t* wb = xb + (size_t)M_ * K_;          // N_*K_ bf16 = 32 MiB

  cvt_x_kernel<<<(int)(((size_t)M_ * K_) / (256 * 8)), 256, 0, stream>>>(x, xb);
  dequant_kernel<<<(int)(((size_t)N_ * K_) / (256 * 8)), 256, 0, stream>>>(qw, sc, wb);

  const int nwg = (N_ / BN) * (M_ / BM);  // 16 * 32 = 512
  gemm_kernel<<<nwg, 512, 0, stream>>>(xb, wb, bias, out);
}

// Round 5
// 471.087 us; speedup vs baseline: 1.0857x; 1.0857x over previous
//
#include <hip/hip_runtime.h>
#include <hip/hip_bf16.h>

typedef __bf16 bf16_t;
typedef __bf16 bf16x8 __attribute__((ext_vector_type(8)));
typedef float  f32x4  __attribute__((ext_vector_type(4)));
typedef int    i32x4  __attribute__((ext_vector_type(4)));

static constexpr int M_ = 8192;   // 4 * 2048
static constexpr int N_ = 4096;   // out_f
static constexpr int K_ = 4096;   // in_f

// GEMM geometry: 256x256 tile, BK=64, 8 waves (2M x 4N), 512 threads.
static constexpr int BM = 256, BN = 256, BK = 64;
static constexpr int NT = K_ / BK;             // 64 K-tiles
static constexpr int HT_ELEMS  = 128 * 64;     // 8192 elems per half-tile
static constexpr int BUF_ELEMS = 2 * HT_ELEMS; // 16384 elems per K-tile buffer

// async global->LDS, 16B per lane. LDS dest must be wave-uniform base + lane*16.
__device__ __forceinline__ void load_lds16(const bf16_t* g, bf16_t* l) {
  __builtin_amdgcn_global_load_lds(
      (const __attribute__((address_space(1))) void*)g,
      (__attribute__((address_space(3))) void*)l,
      16, 0, 0);
}

#define MFMA16(a, b, c) __builtin_amdgcn_mfma_f32_16x16x32_bf16((a), (b), (c), 0, 0, 0)

// ---- pass 1: x fp32 -> bf16 (nt loads: read-once, keep out of L2/L3) -----
__global__ __launch_bounds__(256) void cvt_x_kernel(const float* __restrict__ x,
                                                    bf16_t* __restrict__ xb) {
  const size_t i = ((size_t)blockIdx.x * 256 + threadIdx.x) * 8;
  const f32x4 f0 = __builtin_nontemporal_load((const f32x4*)(x + i));
  const f32x4 f1 = __builtin_nontemporal_load((const f32x4*)(x + i + 4));
  bf16x8 o;
  o[0] = (bf16_t)f0[0]; o[1] = (bf16_t)f0[1]; o[2] = (bf16_t)f0[2]; o[3] = (bf16_t)f0[3];
  o[4] = (bf16_t)f1[0]; o[5] = (bf16_t)f1[1]; o[6] = (bf16_t)f1[2]; o[7] = (bf16_t)f1[3];
  *(bf16x8*)(xb + i) = o;   // cached store: gemm re-reads this soon
}

// ---- pass 2: W[o][i] = q[o][i] * scales[o][i/128] -> bf16 ----------------
__global__ __launch_bounds__(256) void dequant_kernel(const int* __restrict__ q,
                                                      const float* __restrict__ s,
                                                      bf16_t* __restrict__ wb) {
  const size_t base = ((size_t)blockIdx.x * 256 + threadIdx.x) * 8;
  const int o  = (int)(base >> 12);
  const int ii = (int)(base & 4095);
  const float sc = s[(o << 5) + (ii >> 7)];
  const i32x4 q0 = __builtin_nontemporal_load((const i32x4*)(q + base));
  const i32x4 q1 = __builtin_nontemporal_load((const i32x4*)(q + base + 4));
  bf16x8 w;
  w[0] = (bf16_t)((float)q0[0] * sc); w[1] = (bf16_t)((float)q0[1] * sc);
  w[2] = (bf16_t)((float)q0[2] * sc); w[3] = (bf16_t)((float)q0[3] * sc);
  w[4] = (bf16_t)((float)q1[0] * sc); w[5] = (bf16_t)((float)q1[1] * sc);
  w[6] = (bf16_t)((float)q1[2] * sc); w[7] = (bf16_t)((float)q1[3] * sc);
  *(bf16x8*)(wb + base) = w;  // cached store: gemm re-reads this soon
}

// ---- pass 3: C = A . B^T + bias, m201-style 8-phase schedule --------------
// (round-2 structure, best measured: 260 us, MfmaUtil 46%, 0 bank conflicts)
// Fragment interleave:
//   A frag i (0..7): row = (i>>2)*128 + (i&3)*32 + wm*16
//   B frag j (0..3): row = (j>>1)*128 + wn*32 + (j&1)*16
__global__ __launch_bounds__(512, 2) void gemm_kernel(const bf16_t* __restrict__ A,
                                                      const bf16_t* __restrict__ B,
                                                      const float* __restrict__ bias,
                                                      float* __restrict__ C) {
  __shared__ __align__(16) bf16_t As[2 * BUF_ELEMS];  // 64 KiB
  __shared__ __align__(16) bf16_t Bs[2 * BUF_ELEMS];  // 64 KiB

  const int tid  = threadIdx.x;
  const int lane = tid & 63;
  const int wave = tid >> 6;
  const int ln = lane & 15;
  const int lq = lane >> 4;
  const int wm = wave >> 2;   // 0..1
  const int wn = wave & 3;    // 0..3

  // T1: XCD-bijective swizzle (512 wgs = 8 XCD x 64).
  const int bid = blockIdx.x;
  const int wg  = (bid & 7) * 64 + (bid >> 3);
  const int bn  = (wg & 15) * BN;
  const int bm  = (wg >> 4) * BM;

  // staging: thread t covers row (t>>3) of a 64-row chunk, 16B at inverse-swizzled col.
  const int r_sub = tid >> 3;
  const int g_col = ((tid & 7) ^ (r_sub & 7)) * 8;
  const size_t a_base = (size_t)(bm + r_sub) * K_ + g_col;
  const size_t b_base = (size_t)(bn + r_sub) * K_ + g_col;
  const int lds_off = tid * 8;

  auto stageA = [&](int t, int h) {
    bf16_t* d = As + (t & 1) * BUF_ELEMS + h * HT_ELEMS + lds_off;
    const bf16_t* s = A + a_base + (size_t)(h * 128) * K_ + (size_t)t * BK;
    load_lds16(s, d);
    load_lds16(s + (size_t)64 * K_, d + 4096);
  };
  auto stageB = [&](int t, int h) {
    bf16_t* d = Bs + (t & 1) * BUF_ELEMS + h * HT_ELEMS + lds_off;
    const bf16_t* s = B + b_base + (size_t)(h * 128) * K_ + (size_t)t * BK;
    load_lds16(s, d);
    load_lds16(s + (size_t)64 * K_, d + 4096);
  };

  // ds_read addressing (T2 swizzle on the k-column within each 64-elem row)
  const int kx0 = (lq * 8) ^ ((ln & 7) * 8);
  const int kx1 = (32 + lq * 8) ^ ((ln & 7) * 8);
  const int a_row_off = (wm * 16 + ln) * 64;
  const int b_row_off = (wn * 32 + ln) * 64;

  f32x4 acc[8][4] = {};

  // prologue: tile0 {A0,B0,B1,A1} + tile1 {A0,B0,B1}; retire tile0, 3 HT in flight.
  stageA(0, 0); stageB(0, 0); stageB(0, 1); stageA(0, 1);
  stageA(1, 0); stageB(1, 0); stageB(1, 1);
  asm volatile("s_waitcnt vmcnt(6)" ::: "memory");
  __builtin_amdgcn_s_barrier();

  for (int T = 0; T < NT; ++T) {
    const bf16_t* as = As + (T & 1) * BUF_ELEMS;
    const bf16_t* bs = Bs + (T & 1) * BUF_ELEMS;
    bf16x8 af[4][2], bqA[2][2], bqB[2][2];

    // ---- phase 1: read A-half0 (8) + B-half0 (4); stage A1[T+1]; mfma i0-3 x j0-1
#pragma unroll
    for (int i = 0; i < 4; ++i) {
      const bf16_t* p = as + a_row_off + i * 2048;
      af[i][0] = *(const bf16x8*)(p + kx0);
      af[i][1] = *(const bf16x8*)(p + kx1);
    }
#pragma unroll
    for (int j = 0; j < 2; ++j) {
      const bf16_t* p = bs + b_row_off + j * 1024;
      bqA[j][0] = *(const bf16x8*)(p + kx0);
      bqA[j][1] = *(const bf16x8*)(p + kx1);
    }
    if (T + 1 < NT) stageA(T + 1, 1);
    asm volatile("s_waitcnt lgkmcnt(8)" ::: "memory");
    __builtin_amdgcn_s_barrier();
    asm volatile("s_waitcnt lgkmcnt(0)" ::: "memory");
    __builtin_amdgcn_sched_barrier(0);
    __builtin_amdgcn_s_setprio(1);
#pragma unroll
    for (int i = 0; i < 4; ++i)
#pragma unroll
      for (int j = 0; j < 2; ++j) {
        acc[i][j] = MFMA16(af[i][0], bqA[j][0], acc[i][j]);
        acc[i][j] = MFMA16(af[i][1], bqA[j][1], acc[i][j]);
      }
    __builtin_amdgcn_s_setprio(0);
    __builtin_amdgcn_s_barrier();

    // ---- phase 2: read B-half1 (4); stage A0[T+2]; mfma i0-3 x j2-3
#pragma unroll
    for (int j = 0; j < 2; ++j) {
      const bf16_t* p = bs + HT_ELEMS + b_row_off + j * 1024;
      bqB[j][0] = *(const bf16x8*)(p + kx0);
      bqB[j][1] = *(const bf16x8*)(p + kx1);
    }
    if (T + 2 < NT) stageA(T + 2, 0);
    __builtin_amdgcn_s_barrier();
    asm volatile("s_waitcnt lgkmcnt(0)" ::: "memory");
    __builtin_amdgcn_sched_barrier(0);
    __builtin_amdgcn_s_setprio(1);
#pragma unroll
    for (int i = 0; i < 4; ++i)
#pragma unroll
      for (int j = 0; j < 2; ++j) {
        acc[i][j + 2] = MFMA16(af[i][0], bqB[j][0], acc[i][j + 2]);
        acc[i][j + 2] = MFMA16(af[i][1], bqB[j][1], acc[i][j + 2]);
      }
    __builtin_amdgcn_s_setprio(0);
    __builtin_amdgcn_s_barrier();

    // ---- phase 3: read A-half1 (8, reuse af regs); stage B0[T+2]; mfma i4-7 x j2-3
#pragma unroll
    for (int i = 0; i < 4; ++i) {
      const bf16_t* p = as + HT_ELEMS + a_row_off + i * 2048;
      af[i][0] = *(const bf16x8*)(p + kx0);
      af[i][1] = *(const bf16x8*)(p + kx1);
    }
    if (T + 2 < NT) stageB(T + 2, 0);
    __builtin_amdgcn_s_barrier();
    asm volatile("s_waitcnt lgkmcnt(0)" ::: "memory");
    __builtin_amdgcn_sched_barrier(0);
    __builtin_amdgcn_s_setprio(1);
#pragma unroll
    for (int i = 0; i < 4; ++i)
#pragma unroll
      for (int j = 0; j < 2; ++j) {
        acc[i + 4][j + 2] = MFMA16(af[i][0], bqB[j][0], acc[i + 4][j + 2]);
        acc[i + 4][j + 2] = MFMA16(af[i][1], bqB[j][1], acc[i + 4][j + 2]);
      }
    __builtin_amdgcn_s_setprio(0);
    __builtin_amdgcn_s_barrier();

    // ---- phase 4: no reads; stage B1[T+2]; boundary counted wait; mfma i4-7 x j0-1
    if (T + 2 < NT) {
      stageB(T + 2, 1);
      // retires through A1[T+1] (everything tile T+1 reads); keeps
      // A0/B0/B1[T+2] (3 half-tiles = 6 loads) in flight across the barrier.
      asm volatile("s_waitcnt vmcnt(6)" ::: "memory");
    } else {
      asm volatile("s_waitcnt vmcnt(0)" ::: "memory");  // epilogue drain
    }
    __builtin_amdgcn_s_barrier();
    __builtin_amdgcn_sched_barrier(0);
    __builtin_amdgcn_s_setprio(1);
#pragma unroll
    for (int i = 0; i < 4; ++i)
#pragma unroll
      for (int j = 0; j < 2; ++j) {
        acc[i + 4][j] = MFMA16(af[i][0], bqA[j][0], acc[i + 4][j]);
        acc[i + 4][j] = MFMA16(af[i][1], bqA[j][1], acc[i + 4][j]);
      }
    __builtin_amdgcn_s_setprio(0);
    __builtin_amdgcn_s_barrier();
  }

  // epilogue: C/D layout col=lane&15, row=(lane>>4)*4+reg  [m89/m91 verified]
  // nt stores: C is write-once, keep it from evicting A/B panels in L2/L3.
#pragma unroll
  for (int j = 0; j < 4; ++j) {
    const int col = bn + (j >> 1) * 128 + wn * 32 + (j & 1) * 16 + ln;
    const float bv = bias[col];
#pragma unroll
    for (int i = 0; i < 8; ++i) {
      const int row0 = bm + (i >> 2) * 128 + (i & 3) * 32 + wm * 16 + lq * 4;
      float* cp = C + (size_t)row0 * N_ + col;
#pragma unroll
      for (int r = 0; r < 4; ++r) {
        __builtin_nontemporal_store(acc[i][j][r] + bv, cp);
        cp += N_;
      }
    }
  }
}

extern "C" void kernel_launch(void* const* d_in, const int* in_sizes, int n_in,
                              void* d_out, int out_size, void* d_ws, size_t ws_size,
                              hipStream_t stream) {
  const float* x    = (const float*)d_in[0];  // [4,2048,4096] fp32
  const int*   qw   = (const int*)d_in[1];    // [4096,4096] int32 in [0,16)
  const float* sc   = (const float*)d_in[2];  // [4096,32] fp32
  const float* bias = (const float*)d_in[3];  // [4096] fp32
  float* out = (float*)d_out;                 // [8192,4096] fp32

  bf16_t* xb = (bf16_t*)d_ws;                 // M_*K_ bf16 = 64 MiB
  bf16_t* wb = xb + (size_t)M_ * K_;          // N_*K_ bf16 = 32 MiB

  cvt_x_kernel<<<(int)(((size_t)M_ * K_) / (256 * 8)), 256, 0, stream>>>(x, xb);
  dequant_kernel<<<(int)(((size_t)N_ * K_) / (256 * 8)), 256, 0, stream>>>(qw, sc, wb);

  const int nwg = (N_ / BN) * (M_ / BM);  // 16 * 32 = 512
  gemm_kernel<<<nwg, 512, 0, stream>>>(xb, wb, bias, out);
}